// Round 20
// baseline (60.220 us; speedup 1.0000x reference)
//
#include <hip/hip_runtime.h>
#include <hip/hip_bf16.h>
#include <cstdint>
#include <cstddef>

#define BATCH 16
#define NROWS 4096
#define MROWS 2048
#define DDIM  256
#define NSPLIT 2
#define BM 128
#define BN 128
#define NCHUNKS 16           // (NROWS/NSPLIT)/BM

typedef __attribute__((ext_vector_type(8)))  int   i32x8;
typedef __attribute__((ext_vector_type(16))) float f32x16;

// ---------------- Kernel 1: row L2-normalize + fp8(e4m3) cast ----------------
__global__ void __launch_bounds__(256) norm_cast(
    const float* __restrict__ x1, const float* __restrict__ x2,
    unsigned char* __restrict__ aout, unsigned char* __restrict__ bout) {
  const int wid  = threadIdx.x >> 6;
  const int lane = threadIdx.x & 63;
  const long long row = (long long)blockIdx.x * 4 + wid;
  const long long R1 = (long long)BATCH * NROWS;
  const long long R2 = (long long)BATCH * MROWS;
  if (row >= R1 + R2) return;
  const float* src; unsigned char* dst;
  if (row < R1) { src = x1 + row * DDIM; dst = aout + row * DDIM; }
  else { long long r2 = row - R1; src = x2 + r2 * DDIM; dst = bout + r2 * DDIM; }
  float4 v = ((const float4*)src)[lane];
  float ss = v.x*v.x + v.y*v.y + v.z*v.z + v.w*v.w;
  #pragma unroll
  for (int o = 32; o >= 1; o >>= 1) ss += __shfl_xor(ss, o, 64);
  float sc = 1.0f / fmaxf(sqrtf(ss), 1e-12f);
  // HW fp32->fp8 e4m3 (OCP on gfx950), RNE.
  int r = __builtin_amdgcn_cvt_pk_fp8_f32(v.x * sc, v.y * sc, 0, false);
  r = __builtin_amdgcn_cvt_pk_fp8_f32(v.z * sc, v.w * sc, r, true);
  ((unsigned int*)dst)[lane] = (unsigned int)r;
}

// ---------------- Kernel 2: MX-fp8 GEMM 128x128, 2 blocks/CU ----------------
typedef __attribute__((address_space(1))) const void gas_t;
typedef __attribute__((address_space(3))) void las_t;
#define GLL16(g, l) __builtin_amdgcn_global_load_lds((gas_t*)(g), (las_t*)(l), 16, 0, 0)

// LDS: 4 A ring slots [128 rows][64 B] = 8 KB each; 4 resident B slots = 8 KB.
// Total 64 KB/block -> 2 independent blocks per CU (TLP hides barrier stalls).
#define LDSA(S) (lds + ((S) << 13))
#define LDSB(S) (lds + 32768 + ((S) << 13))

// 32x32x64 fragment read: lane holds row (l&31), k-bytes (l>>5)*32..+31.
// k-slots XOR-swizzled by row bits 1-2 (matches staging pre-swizzle).
static __device__ __forceinline__ i32x8 frag8(const char* slot, int row, int lane) {
  const int rb = (lane >> 1) & 3;
  const int ks = lane >> 5;
  const char* base = slot + row * 64;
  uint4 u0 = *(const uint4*)(base + ((((ks << 1) | 0) ^ rb) << 4));
  uint4 u1 = *(const uint4*)(base + ((((ks << 1) | 1) ^ rb) << 4));
  i32x8 r;
  r[0] = u0.x; r[1] = u0.y; r[2] = u0.z; r[3] = u0.w;
  r[4] = u1.x; r[5] = u1.y; r[6] = u1.z; r[7] = u1.w;
  return r;
}

__global__ void __launch_bounds__(512, 4) maxsim_fp8(
    const unsigned char* __restrict__ A,    // [BATCH][NROWS][DDIM] fp8
    const unsigned char* __restrict__ Bm,   // [BATCH][MROWS][DDIM] fp8
    float* __restrict__ partials)           // [NSPLIT][BATCH][MROWS]
{
  __shared__ __align__(16) char lds[65536];

  const int t = threadIdx.x;
  const int lane = t & 63;
  const int w = t >> 6;
  const int wr = w >> 2;     // n-half (wave owns 64 rows): 0..1
  const int wc = w & 3;      // m-quarter (wave owns 32 cols): 0..3
  const int l31 = lane & 31;

  // XCD-aware bijective swizzle: 512 blocks, XCD k owns batches {2k,2k+1}.
  const int hw = blockIdx.x;
  const int logical = (hw & 7) * 64 + (hw >> 3);
  const int mt = logical & 15;
  const int grp = logical >> 4;    // 0..31
  const int sp = grp & 1;
  const int bb = grp >> 1;

  const int m0 = mt * BN;
  const int nbase = sp * (NROWS / NSPLIT);

  const unsigned char* Aba = A  + (size_t)bb * NROWS * DDIM;
  const unsigned char* Bba = Bm + ((size_t)bb * MROWS + m0) * DDIM;

  // Staging: slot [128 rows][64 B] = 8 KB = 512 thr x 1 x 16 B.
  // row = t>>2, 16B k-slot kq = t&3, source pre-swizzled:
  // sphys = kq ^ ((row>>1)&3) = kq ^ ((t>>3)&3).
  const int srow = t >> 2;
  const int sph = (((t & 3) ^ ((t >> 3) & 3)) << 4);   // bytes
  const unsigned char* sAr = Aba + (size_t)srow * DDIM + sph;
  const unsigned char* sBr = Bba + (size_t)srow * DDIM + sph;
  const int ldst = t * 16;   // slot-relative LDS dest (wave-linear)

  #define STAGE_A(SL, OFF) GLL16(sAr + (OFF), (SL) + ldst)
  #define STAGE_B(SL, OFF) GLL16(sBr + (OFF), (SL) + ldst)

  f32x16 acc[2] = {};
  const f32x16 z16 = {};
  i32x8 af[2], bf;
  float cm = -INFINITY;

  // ---- Prologue: A tiles 0,1 -> ring slots 0,1; ALL of B (4 slots, resident).
  STAGE_A(LDSA(0), (size_t)nbase * DDIM + 0);
  STAGE_B(LDSB(0), 0);
  STAGE_B(LDSB(1), 64);
  STAGE_B(LDSB(2), 128);
  STAGE_B(LDSB(3), 192);
  STAGE_A(LDSA(1), (size_t)nbase * DDIM + 64);
  asm volatile("s_waitcnt vmcnt(1)" ::: "memory");   // A0 + all B landed; A1 in flight
  asm volatile("s_barrier" ::: "memory");

  // Per K-tile(64): 6 ds_reads; stage A for T+2 into ring slot (kt+2)&3
  // (slot held tile T-2, read 2 barriers ago -> WAR-safe); 2 MFMA;
  // vmcnt(1) => T+1's A landed; ONE barrier. 2 blocks/CU overlap stalls.
  for (int nc = 0; nc < NCHUNKS; ++nc) {
    #pragma unroll
    for (int kt = 0; kt < 4; ++kt) {
      const char* sa = LDSA(kt);
      const char* sb = LDSB(kt);
      const int s2 = (kt + 2) & 3;
      const int nc2 = (kt < 2) ? nc : ((nc + 1) & (NCHUNKS - 1));  // junk-wrap tail
      const size_t offA2 = ((size_t)nbase + nc2 * BM) * DDIM + s2 * 64;

      bf = frag8(sb, wc * 32 + l31, lane);
      af[0] = frag8(sa, wr * 64 + l31, lane);
      af[1] = frag8(sa, wr * 64 + 32 + l31, lane);
      STAGE_A(LDSA(s2), offA2);
      acc[0] = __builtin_amdgcn_mfma_scale_f32_32x32x64_f8f6f4(
          af[0], bf, acc[0], 0, 0, 0, 0x7F7F7F7F, 0, 0x7F7F7F7F);  // E8M0 0x7F = 1.0
      acc[1] = __builtin_amdgcn_mfma_scale_f32_32x32x64_f8f6f4(
          af[1], bf, acc[1], 0, 0, 0, 0x7F7F7F7F, 0, 0x7F7F7F7F);
      asm volatile("s_waitcnt vmcnt(1)" ::: "memory");   // T+1's A landed
      asm volatile("s_barrier" ::: "memory");
    }
    // fold chunk's C into running column max; reset acc.
    // C/D 32x32: col = lane&31, 16 regs spread rows, + (lane>>5) offset.
    #pragma unroll
    for (int mi = 0; mi < 2; ++mi) {
      #pragma unroll
      for (int r = 0; r < 16; ++r) cm = fmaxf(cm, acc[mi][r]);
      acc[mi] = z16;
    }
  }

  // ---- Epilogue: drain DMA (incl. junk stages into slots 0/1 that alias
  // cmax); reduce across lane halves + waves; write partials.
  asm volatile("s_waitcnt vmcnt(0)" ::: "memory");
  asm volatile("s_barrier" ::: "memory");
  cm = fmaxf(cm, __shfl_xor(cm, 32, 64));
  float* cmax = (float*)lds;   // [2][128]
  if (lane < 32)
    cmax[wr * 128 + wc * 32 + l31] = cm;
  __syncthreads();
  if (t < BN) {
    float v = fmaxf(cmax[t], cmax[128 + t]);
    partials[((size_t)sp * BATCH + bb) * MROWS + m0 + t] = v;
  }
}

// ---------------- Kernel 3a: per-batch loss ----------------
__global__ void __launch_bounds__(256) batch_loss(
    const float* __restrict__ partials, const float* __restrict__ y,
    float* __restrict__ bloss) {
  __shared__ float red[4];
  const int b = blockIdx.x;
  const int t = threadIdx.x;
  const int lane = t & 63;
  const int w = t >> 6;
  float s = 0.0f;
  for (int m = t; m < MROWS; m += 256) {
    float v = partials[(size_t)b * MROWS + m];
    #pragma unroll
    for (int sp = 1; sp < NSPLIT; ++sp)
      v = fmaxf(v, partials[((size_t)sp * BATCH + b) * MROWS + m]);
    s += v;
  }
  #pragma unroll
  for (int o = 32; o >= 1; o >>= 1) s += __shfl_xor(s, o, 64);
  if (lane == 0) red[w] = s;
  __syncthreads();
  if (t == 0) {
    float sum = red[0] + red[1] + red[2] + red[3];
    float mean = sum / (float)MROWS;
    float yb = y[b];
    float d = mean - yb;
    bloss[b] = d * d;   // Y_SCALE == 1.0
  }
}

// ---------------- Kernel 3b: combine per-batch losses ----------------
__global__ void __launch_bounds__(64) final_sum(
    const float* __restrict__ bloss, float* __restrict__ out) {
  const int t = threadIdx.x;
  float v = (t < BATCH) ? bloss[t] : 0.0f;
  #pragma unroll
  for (int o = 32; o >= 1; o >>= 1) v += __shfl_xor(v, o, 64);
  if (t == 0) out[0] = v;
}

extern "C" void kernel_launch(void* const* d_in, const int* in_sizes, int n_in,
                              void* d_out, int out_size, void* d_ws, size_t ws_size,
                              hipStream_t stream) {
  const float* x1 = (const float*)d_in[0];
  const float* x2 = (const float*)d_in[1];
  const float* y  = (const float*)d_in[2];
  float* out = (float*)d_out;

  unsigned char* aF8 = (unsigned char*)d_ws;                          // 16 MB
  unsigned char* bF8 = aF8 + (size_t)BATCH * NROWS * DDIM;            // 8 MB
  float* partials = (float*)(bF8 + (size_t)BATCH * MROWS * DDIM);     // 256 KB
  float* bloss = partials + (size_t)NSPLIT * BATCH * MROWS;

  const int totRows = BATCH * (NROWS + MROWS);
  norm_cast<<<(totRows + 3) / 4, 256, 0, stream>>>(x1, x2, aF8, bF8);
  maxsim_fp8<<<BATCH * 16 * NSPLIT, 512, 0, stream>>>(aF8, bF8, partials);
  batch_loss<<<BATCH, 256, 0, stream>>>(partials, y, bloss);
  final_sum<<<1, 64, 0, stream>>>(bloss, out);
}

// Round 21
// 54.196 us; speedup vs baseline: 1.1111x; 1.1111x over previous
//
#include <hip/hip_runtime.h>
#include <hip/hip_bf16.h>
#include <cstdint>
#include <cstddef>

#define BATCH 16
#define NROWS 4096
#define MROWS 2048
#define DDIM  256
#define NSPLIT 2
#define NCHUNKS 8            // (NROWS/NSPLIT)/256

typedef __attribute__((ext_vector_type(8)))  int   i32x8;
typedef __attribute__((ext_vector_type(16))) float f32x16;

// ---------------- Kernel 1: row L2-normalize + fp8(e4m3) cast ----------------
__global__ void __launch_bounds__(256) norm_cast(
    const float* __restrict__ x1, const float* __restrict__ x2,
    unsigned char* __restrict__ aout, unsigned char* __restrict__ bout) {
  const int wid  = threadIdx.x >> 6;
  const int lane = threadIdx.x & 63;
  const long long row = (long long)blockIdx.x * 4 + wid;
  const long long R1 = (long long)BATCH * NROWS;
  const long long R2 = (long long)BATCH * MROWS;
  if (row >= R1 + R2) return;
  const float* src; unsigned char* dst;
  if (row < R1) { src = x1 + row * DDIM; dst = aout + row * DDIM; }
  else { long long r2 = row - R1; src = x2 + r2 * DDIM; dst = bout + r2 * DDIM; }
  float4 v = ((const float4*)src)[lane];
  float ss = v.x*v.x + v.y*v.y + v.z*v.z + v.w*v.w;
  #pragma unroll
  for (int o = 32; o >= 1; o >>= 1) ss += __shfl_xor(ss, o, 64);
  float sc = 1.0f / fmaxf(sqrtf(ss), 1e-12f);
  // HW fp32->fp8 e4m3 (OCP on gfx950), RNE.
  int r = __builtin_amdgcn_cvt_pk_fp8_f32(v.x * sc, v.y * sc, 0, false);
  r = __builtin_amdgcn_cvt_pk_fp8_f32(v.z * sc, v.w * sc, r, true);
  ((unsigned int*)dst)[lane] = (unsigned int)r;
}

// ---------------- Kernel 2: MX-fp8 GEMM, B-resident LDS + 4-slot A-ring ----------------
typedef __attribute__((address_space(1))) const void gas_t;
typedef __attribute__((address_space(3))) void las_t;
#define GLL16(g, l) __builtin_amdgcn_global_load_lds((gas_t*)(g), (las_t*)(l), 16, 0, 0)

// LDS: 4 A ring slots [256 rows][64 B] = 16 KB each; 4 resident B slots.
#define LDSA(S) (lds + ((S) << 14))
#define LDSB(S) (lds + 65536 + ((S) << 14))

// 32x32x64 fragment read: lane holds row (l&31), k-bytes (l>>5)*32..+31.
// k-slots XOR-swizzled by row bits 1-2 (matches staging pre-swizzle).
static __device__ __forceinline__ i32x8 frag8(const char* slot, int row, int lane) {
  const int rb = (lane >> 1) & 3;
  const int ks = lane >> 5;
  const char* base = slot + row * 64;
  uint4 u0 = *(const uint4*)(base + ((((ks << 1) | 0) ^ rb) << 4));
  uint4 u1 = *(const uint4*)(base + ((((ks << 1) | 1) ^ rb) << 4));
  i32x8 r;
  r[0] = u0.x; r[1] = u0.y; r[2] = u0.z; r[3] = u0.w;
  r[4] = u1.x; r[5] = u1.y; r[6] = u1.z; r[7] = u1.w;
  return r;
}

__global__ void __launch_bounds__(512, 1) maxsim_fp8(
    const unsigned char* __restrict__ A,    // [BATCH][NROWS][DDIM] fp8
    const unsigned char* __restrict__ Bm,   // [BATCH][MROWS][DDIM] fp8
    float* __restrict__ partials)           // [NSPLIT][BATCH][MROWS]
{
  __shared__ __align__(16) char lds[131072];

  const int t = threadIdx.x;
  const int lane = t & 63;
  const int w = t >> 6;
  const int wr = w >> 2;     // n-half (wave owns 128 rows)
  const int wc = w & 3;      // m-quarter (wave owns 64 cols)
  const int l31 = lane & 31;

  // XCD-aware bijective swizzle: 256 blocks, XCD k owns batches {2k,2k+1}.
  const int hw = blockIdx.x;
  const int logical = (hw & 7) * 32 + (hw >> 3);
  const int mt = logical & 7;
  const int grp = logical >> 3;
  const int sp = grp & 1;
  const int bb = grp >> 1;

  const int m0 = mt * 256;
  const int nbase = sp * (NROWS / NSPLIT);

  const unsigned char* Aba = A  + (size_t)bb * NROWS * DDIM;
  const unsigned char* Bba = Bm + ((size_t)bb * MROWS + m0) * DDIM;

  // Staging: slot [256 rows][64 B]; 512 thr x 2 x 16B = 16 KB per slot-fill.
  // chunk c = w*2+i covers rows c*16 + (lane>>2); 16B k-slot kq = lane&3,
  // source pre-swizzled: sphys = kq ^ ((row>>1)&3) = kq ^ ((lane>>3)&3).
  const int r0 = (w * 2 + 0) * 16 + (lane >> 2);
  const int r1 = (w * 2 + 1) * 16 + (lane >> 2);
  const int sph = (((lane & 3) ^ ((lane >> 3) & 3)) << 4);   // bytes
  const unsigned char* sA0 = Aba + (size_t)r0 * DDIM + sph;
  const unsigned char* sA1 = Aba + (size_t)r1 * DDIM + sph;
  const unsigned char* sB0 = Bba + (size_t)r0 * DDIM + sph;
  const unsigned char* sB1 = Bba + (size_t)r1 * DDIM + sph;
  const int l0 = (w * 2 + 0) * 1024 + lane * 16;   // slot-relative LDS dest
  const int l1 = (w * 2 + 1) * 1024 + lane * 16;

  #define STAGE_A(SLOT, OFF) do { \
    GLL16(sA0 + (OFF), (SLOT) + l0); GLL16(sA1 + (OFF), (SLOT) + l1); } while (0)
  #define STAGE_B(SLOT, OFF) do { \
    GLL16(sB0 + (OFF), (SLOT) + l0); GLL16(sB1 + (OFF), (SLOT) + l1); } while (0)

  f32x16 acc[4][2] = {};
  const f32x16 z16 = {};
  i32x8 af[4], bf[2];
  float cm[2] = {-INFINITY, -INFINITY};

  // ---- Prologue: A tiles 0,1 -> ring slots 0,1; ALL of B (4 slots, resident).
  STAGE_A(LDSA(0), (size_t)nbase * DDIM + 0);
  STAGE_B(LDSB(0), 0);
  STAGE_B(LDSB(1), 64);
  STAGE_B(LDSB(2), 128);
  STAGE_B(LDSB(3), 192);
  STAGE_A(LDSA(1), (size_t)nbase * DDIM + 64);
  asm volatile("s_waitcnt vmcnt(8)" ::: "memory");   // A0+B0 (oldest 4) landed
  asm volatile("s_barrier" ::: "memory");

  // Per K-tile(64): 12 ds_reads; stage A for T+2 into ring slot (kt+2)&3
  // (WAR distance = 2 barriers); 8 MFMA (compiler-progressive lgkm waits);
  // vmcnt(2) => T+1's A landed; ONE barrier.
  for (int nc = 0; nc < NCHUNKS; ++nc) {
    #pragma unroll
    for (int kt = 0; kt < 4; ++kt) {
      const char* sa = LDSA(kt);
      const char* sb = LDSB(kt);
      const int s2 = (kt + 2) & 3;
      const int nc2 = (kt < 2) ? nc : ((nc + 1) & (NCHUNKS - 1));  // junk-wrap tail
      const size_t offA2 = ((size_t)nbase + nc2 * 256) * DDIM + s2 * 64;

      #pragma unroll
      for (int nj = 0; nj < 2; ++nj)
        bf[nj] = frag8(sb, wc * 64 + nj * 32 + l31, lane);
      #pragma unroll
      for (int mi = 0; mi < 4; ++mi)
        af[mi] = frag8(sa, wr * 128 + mi * 32 + l31, lane);
      STAGE_A(LDSA(s2), offA2);
      #pragma unroll
      for (int mi = 0; mi < 4; ++mi)
        #pragma unroll
        for (int nj = 0; nj < 2; ++nj)
          acc[mi][nj] = __builtin_amdgcn_mfma_scale_f32_32x32x64_f8f6f4(
              af[mi], bf[nj], acc[mi][nj], 0, 0,
              0, 0x7F7F7F7F, 0, 0x7F7F7F7F);   // E8M0 0x7F = scale 1.0
      asm volatile("s_waitcnt vmcnt(2)" ::: "memory");   // T+1's A landed
      asm volatile("s_barrier" ::: "memory");
    }
    // fold chunk's C into running column max; reset acc.
    // C/D 32x32: col = lane&31, 16 regs spread rows, + (lane>>5) offset.
    #pragma unroll
    for (int nj = 0; nj < 2; ++nj) {
      float v = cm[nj];
      #pragma unroll
      for (int mi = 0; mi < 4; ++mi) {
        #pragma unroll
        for (int r = 0; r < 16; ++r) v = fmaxf(v, acc[mi][nj][r]);
        acc[mi][nj] = z16;
      }
      cm[nj] = v;
    }
  }

  // ---- Epilogue: drain DMA; reduce across lane halves + waves; write partials.
  asm volatile("s_waitcnt vmcnt(0)" ::: "memory");
  asm volatile("s_barrier" ::: "memory");
  #pragma unroll
  for (int nj = 0; nj < 2; ++nj)
    cm[nj] = fmaxf(cm[nj], __shfl_xor(cm[nj], 32, 64));
  float* cmax = (float*)lds;   // [2][256]
  if (lane < 32) {
    cmax[wr * 256 + wc * 64 + l31]      = cm[0];
    cmax[wr * 256 + wc * 64 + 32 + l31] = cm[1];
  }
  __syncthreads();
  if (t < 256) {
    float v = fmaxf(cmax[t], cmax[256 + t]);
    partials[((size_t)sp * BATCH + bb) * MROWS + m0 + t] = v;
  }
}

// ---------------- Kernel 3a: per-batch loss ----------------
__global__ void __launch_bounds__(256) batch_loss(
    const float* __restrict__ partials, const float* __restrict__ y,
    float* __restrict__ bloss) {
  __shared__ float red[4];
  const int b = blockIdx.x;
  const int t = threadIdx.x;
  const int lane = t & 63;
  const int w = t >> 6;
  float s = 0.0f;
  for (int m = t; m < MROWS; m += 256) {
    float v = partials[(size_t)b * MROWS + m];
    #pragma unroll
    for (int sp = 1; sp < NSPLIT; ++sp)
      v = fmaxf(v, partials[((size_t)sp * BATCH + b) * MROWS + m]);
    s += v;
  }
  #pragma unroll
  for (int o = 32; o >= 1; o >>= 1) s += __shfl_xor(s, o, 64);
  if (lane == 0) red[w] = s;
  __syncthreads();
  if (t == 0) {
    float sum = red[0] + red[1] + red[2] + red[3];
    float mean = sum / (float)MROWS;
    float yb = y[b];
    float d = mean - yb;
    bloss[b] = d * d;   // Y_SCALE == 1.0
  }
}

// ---------------- Kernel 3b: combine per-batch losses ----------------
__global__ void __launch_bounds__(64) final_sum(
    const float* __restrict__ bloss, float* __restrict__ out) {
  const int t = threadIdx.x;
  float v = (t < BATCH) ? bloss[t] : 0.0f;
  #pragma unroll
  for (int o = 32; o >= 1; o >>= 1) v += __shfl_xor(v, o, 64);
  if (t == 0) out[0] = v;
}

extern "C" void kernel_launch(void* const* d_in, const int* in_sizes, int n_in,
                              void* d_out, int out_size, void* d_ws, size_t ws_size,
                              hipStream_t stream) {
  const float* x1 = (const float*)d_in[0];
  const float* x2 = (const float*)d_in[1];
  const float* y  = (const float*)d_in[2];
  float* out = (float*)d_out;

  unsigned char* aF8 = (unsigned char*)d_ws;                          // 16 MB
  unsigned char* bF8 = aF8 + (size_t)BATCH * NROWS * DDIM;            // 8 MB
  float* partials = (float*)(bF8 + (size_t)BATCH * MROWS * DDIM);     // 256 KB
  float* bloss = partials + (size_t)NSPLIT * BATCH * MROWS;

  const int totRows = BATCH * (NROWS + MROWS);
  norm_cast<<<(totRows + 3) / 4, 256, 0, stream>>>(x1, x2, aF8, bF8);
  maxsim_fp8<<<BATCH * 8 * NSPLIT, 512, 0, stream>>>(aF8, bF8, partials);
  batch_loss<<<BATCH, 256, 0, stream>>>(partials, y, bloss);
  final_sum<<<1, 64, 0, stream>>>(bloss, out);
}